// Round 16
// baseline (152.541 us; speedup 1.0000x reference)
//
#include <hip/hip_runtime.h>

// B=8, C=512, H=W=32, HW=1024, M=8192. scale = 1/sqrt(512).
// prep (x transpose->bf16, W pack->bf16)
// gemm_qkz (STAGED R5-hybrid: A per-lane global, B via global_load_lds,
//           8 barriers; q|k -> fp8 qk8 via v_cvt_pk_fp8_f32 (+bias), z -> bf16)
// gemm_scores (R16: SAFE double-buffer per guide's minimum 2-phase template.
//              2 x 32 KB buffers, 64-col phases, 16 phases. Per phase:
//              issue STAGE(next) -> compute(cur) 16 MFMA -> EXPLICIT
//              "s_waitcnt vmcnt(0)" -> barrier -> flip. The explicit drain
//              closes the R4 race class (R4 relied on __syncthreads'
//              implicit drain for global_load_lds and corrupted
//              nondeterministically); DMA latency now hides under compute.
//              (kh,kc) accumulation order == R13 -> bit-identical.)
// epilogue_out (R10 fused softmax + gating + transpose, verified)

typedef __attribute__((ext_vector_type(8))) short bf16x8;
typedef __attribute__((ext_vector_type(4))) float f32x4;
typedef __attribute__((ext_vector_type(2))) long long i64x2;
typedef __attribute__((ext_vector_type(8))) int i32x8;

__device__ __forceinline__ unsigned short f2bf(float f) {
  unsigned u = __builtin_bit_cast(unsigned, f);
  u += 0x7FFFu + ((u >> 16) & 1u);
  return (unsigned short)(u >> 16);
}

__device__ __forceinline__ float bf2f(unsigned short b) {
  return __builtin_bit_cast(float, (unsigned)b << 16);
}

__device__ __forceinline__ void gload_lds16(const void* g, void* l) {
  __builtin_amdgcn_global_load_lds(
      (const __attribute__((address_space(1))) unsigned int*)g,
      (__attribute__((address_space(3))) unsigned int*)l, 16, 0, 0);
}

// ---------------------------------------------------------------------------
// prep: blocks [0,1024): transpose x [b][c][p] -> xt [b*1024+p][c] bf16
//       blocks [1024,1792): pack Wq|Wk|W6 -> wcat bf16 [1536][512]
__global__ __launch_bounds__(256) void prep(const float* __restrict__ x,
                                            const float* __restrict__ Wq,
                                            const float* __restrict__ Wk,
                                            const float* __restrict__ W6,
                                            short* __restrict__ xt,
                                            short* __restrict__ wcat) {
  const int bid = blockIdx.x, u = threadIdx.x;
  if (bid < 1024) {
    const int p0 = (bid & 15) * 64, c0 = ((bid >> 4) & 7) * 64, b = bid >> 7;
    __shared__ float t[64][65];
    {
      const int p4 = u & 15, cr = u >> 4;
      for (int cc = 0; cc < 4; ++cc) {
        const int c = cc * 16 + cr;
        const float4 v = *(const float4*)&x[((size_t)(b * 512 + c0 + c)) * 1024 + p0 + p4 * 4];
        t[p4 * 4 + 0][c] = v.x; t[p4 * 4 + 1][c] = v.y;
        t[p4 * 4 + 2][c] = v.z; t[p4 * 4 + 3][c] = v.w;
      }
    }
    __syncthreads();
    {
      const int c4 = u & 15, pr = u >> 4;
      for (int pp = 0; pp < 4; ++pp) {
        const int p = pp * 16 + pr;
        ushort4 o;
        o.x = f2bf(t[p][c4 * 4 + 0]); o.y = f2bf(t[p][c4 * 4 + 1]);
        o.z = f2bf(t[p][c4 * 4 + 2]); o.w = f2bf(t[p][c4 * 4 + 3]);
        *(ushort4*)&xt[((size_t)(b * 1024 + p0 + p)) * 512 + c0 + c4 * 4] = o;
      }
    }
  } else {
    const int i = (bid - 1024) * 256 + u;
    const int idx = i * 4;
    const float* src = (idx < 262144) ? Wq : (idx < 524288) ? Wk : W6;
    const float4 v = *(const float4*)&src[idx & 262143];
    ushort4 o;
    o.x = f2bf(v.x); o.y = f2bf(v.y); o.z = f2bf(v.z); o.w = f2bf(v.w);
    *(ushort4*)&wcat[idx] = o;
  }
}

// ---------------------------------------------------------------------------
// gemm_qkz: C[8192][1536] = xt @ wcat^T, R5-hybrid structure (staged).
// Block 128x128, grid (64,12); wave w owns rows [m0+w*32,+32): acc[2][8].
// A streamed per-lane from global; B staged in LDS in 4 K-chunks, 32 KB LDS.
// Cols 0..1023 -> qk8 fp8 (+bias, HW v_cvt_pk_fp8_f32); 1024..1535 -> z bf16.
__global__ __launch_bounds__(256) void gemm_qkz(const short* __restrict__ xt,
                                                const short* __restrict__ wcat,
                                                const float* __restrict__ bq,
                                                const float* __restrict__ bk,
                                                unsigned char* __restrict__ qk8,
                                                short* __restrict__ z) {
  __shared__ short lds_b[16384];  // 32 KB: 8 j-groups x 4 kb x 512 shorts
  const int tid = threadIdx.x, w = tid >> 6, lane = tid & 63;
  const int quad = lane >> 4, lcol = lane & 15;
  const int srow = lane & 15, skq = lane >> 4;  // staging: row in j-group, 8-elem quad
  const int m0 = blockIdx.x * 128, n0 = blockIdx.y * 128;

  f32x4 acc[2][8];
#pragma unroll
  for (int rg = 0; rg < 2; ++rg)
#pragma unroll
    for (int j = 0; j < 8; ++j)
#pragma unroll
      for (int r = 0; r < 4; ++r) acc[rg][j][r] = 0.f;

  // A: per-lane; row = m0 + w*32 + rg*16 + srow, k-elems kh*128 + kb*32 + skq*8
  const short* Abase = xt + (size_t)(m0 + w * 32 + srow) * 512 + skq * 8;
  // B: staging source; row = n0 + j*16 + srow
  const short* Bbase = wcat + (size_t)(n0 + srow) * 512 + skq * 8;

#pragma unroll
  for (int kh = 0; kh < 4; ++kh) {
    const int ke = kh * 128;  // k-elem base of this chunk
    __syncthreads();  // previous chunk fully consumed before overwrite
#pragma unroll
    for (int jj = 0; jj < 2; ++jj) {
      const int j = w * 2 + jj;
#pragma unroll
      for (int kb = 0; kb < 4; ++kb)
        gload_lds16(Bbase + (size_t)(j * 16) * 512 + ke + kb * 32,
                    lds_b + j * 2048 + kb * 512);
    }
    // prefetch this chunk's A (2 rg x 4 kb x 16 B) while glds are in flight
    bf16x8 af[2][4];
#pragma unroll
    for (int rg = 0; rg < 2; ++rg)
#pragma unroll
      for (int kb = 0; kb < 4; ++kb)
        af[rg][kb] = *(const bf16x8*)(Abase + (size_t)rg * 16 * 512 + ke + kb * 32);
    __syncthreads();  // B chunk ready
#pragma unroll
    for (int kb = 0; kb < 4; ++kb) {
#pragma unroll
      for (int j = 0; j < 8; ++j) {
        const bf16x8 bf = *(const bf16x8*)&lds_b[j * 2048 + kb * 512 + lane * 8];
#pragma unroll
        for (int rg = 0; rg < 2; ++rg)
          acc[rg][j] = __builtin_amdgcn_mfma_f32_16x16x32_bf16(af[rg][kb], bf, acc[rg][j], 0, 0, 0);
      }
    }
  }

  const int region = (int)blockIdx.y >> 2;  // 0=q, 1=k, 2=z (uniform per block)
  if (region < 2) {
    const float* bias = region ? bk : bq;
#pragma unroll
    for (int rg = 0; rg < 2; ++rg) {
      const int row = m0 + w * 32 + rg * 16 + quad * 4;
#pragma unroll
      for (int j = 0; j < 8; ++j) {
        const int col = n0 + j * 16 + lcol;
        const float bv = bias[col & 511];
        const int p01 = __builtin_amdgcn_cvt_pk_fp8_f32(
            acc[rg][j][0] + bv, acc[rg][j][1] + bv, 0, false);
        const int p23 = __builtin_amdgcn_cvt_pk_fp8_f32(
            acc[rg][j][2] + bv, acc[rg][j][3] + bv, 0, false);
        qk8[(size_t)(row + 0) * 1024 + col] = (unsigned char)(p01 & 0xFF);
        qk8[(size_t)(row + 1) * 1024 + col] = (unsigned char)((p01 >> 8) & 0xFF);
        qk8[(size_t)(row + 2) * 1024 + col] = (unsigned char)(p23 & 0xFF);
        qk8[(size_t)(row + 3) * 1024 + col] = (unsigned char)((p23 >> 8) & 0xFF);
      }
    }
  } else {
#pragma unroll
    for (int rg = 0; rg < 2; ++rg) {
      const int row = m0 + w * 32 + rg * 16 + quad * 4;
#pragma unroll
      for (int j = 0; j < 8; ++j) {
        const int col = n0 - 1024 + j * 16 + lcol;
#pragma unroll
        for (int r = 0; r < 4; ++r)
          z[(size_t)(row + r) * 512 + col] = (short)f2bf(acc[rg][j][r]);
      }
    }
  }
}

// ---------------------------------------------------------------------------
// gemm_scores R16: q @ k^T via MX-fp8 mfma_scale_f32_16x16x128_f8f6f4, unit
// scales. Double-buffered per the guide's minimum 2-phase template with
// EXPLICIT vmcnt(0) drains (closes R4's race class):
//   prologue: STAGE(0 -> buf0); drain; barrier
//   per phase: STAGE(ns+1 -> other buf); compute(cur buf) 16 MFMA;
//              drain vmcnt(0); barrier; flip.
// 2 x 32 KB buffers (64-col phases, 16 phases); internal layout, staging
// split (wave stages j-group w>>1, K-half w&1), lane maps, and per-element
// (kh,kc) accumulation order identical to R13 -> bit-identical output.
// grid (64 row-tiles, 8 images), block 512 = 8 waves; wave w owns rows
// [m0+w*16,+16); A resident af[4]. Per-image row-max -> wsmx[8][8192].
__global__ __launch_bounds__(512) void gemm_scores(const unsigned char* __restrict__ qk8,
                                                   float* __restrict__ wsmx) {
  __shared__ unsigned char lds_b[2][32768];  // per buf: 4 j x 2 kh x 2 kc x 2 p x 1 KB
  const int tid = threadIdx.x, w = tid >> 6, lane = tid & 63;
  const int quad = lane >> 4, lcol = lane & 15;
  const int srow = lane & 15, skb = (lane >> 4) * 32;  // staging row / k-offset
  const int m0 = blockIdx.x * 128;
  const int img = blockIdx.y;  // image = 1024-col stripe
  const int n0 = img * 1024;

  // A resident: row = m0 + w*16 + srow, k-bytes kk*128 + quad*32 + [0,32)
  const unsigned char* Abase = qk8 + (size_t)(m0 + w * 16 + srow) * 1024 + quad * 32;
  i32x8 af[4];
#pragma unroll
  for (int kk = 0; kk < 4; ++kk) af[kk] = *(const i32x8*)(Abase + kk * 128);

  // B staging: wave w stages j-group jg = w>>1, K-half kh2 = w&1.
  // Source row = n0 + ns*64 + jg*16 + srow; k-bytes: kh2*256 + kc*128 + skb + p*16.
  const int jg = w >> 1, kh2 = w & 1;
  const unsigned char* Bbase =
      qk8 + (size_t)(n0 + jg * 16 + srow) * 1024 + 512 + kh2 * 256 + skb;
  unsigned char* dst0 = &lds_b[0][jg * 8192 + kh2 * 4096];
  unsigned char* dst1 = &lds_b[1][jg * 8192 + kh2 * 4096];

  f32x4 acc[4];
  float vmax[4] = {-1e30f, -1e30f, -1e30f, -1e30f};

#define STAGE(ns, dst)                                                        \
  {                                                                           \
    _Pragma("unroll") for (int kc = 0; kc < 2; ++kc)                          \
        _Pragma("unroll") for (int p = 0; p < 2; ++p)                         \
            gload_lds16(Bbase + (ns) * 65536 + kc * 128 + p * 16,             \
                        (dst) + kc * 2048 + p * 1024);                        \
  }
#define DRAINBAR                                      \
  asm volatile("s_waitcnt vmcnt(0)" ::: "memory");    \
  __syncthreads();
#define COMPUTE_PHASE(CB)                                                     \
  {                                                                           \
    _Pragma("unroll") for (int j = 0; j < 4; ++j)                             \
        _Pragma("unroll") for (int r = 0; r < 4; ++r) acc[j][r] = 0.f;        \
    _Pragma("unroll") for (int kh = 0; kh < 2; ++kh)                          \
        _Pragma("unroll") for (int kc = 0; kc < 2; ++kc)                      \
            _Pragma("unroll") for (int j = 0; j < 4; ++j) {                   \
      i32x8 bf;                                                               \
      *(i64x2*)&bf =                                                          \
          *(const i64x2*)&(CB)[j * 8192 + kh * 4096 + kc * 2048 + lane * 16]; \
      *((i64x2*)&bf + 1) =                                                    \
          *(const i64x2*)&(CB)[j * 8192 + kh * 4096 + kc * 2048 + 1024 +      \
                               lane * 16];                                    \
      acc[j] = __builtin_amdgcn_mfma_scale_f32_16x16x128_f8f6f4(              \
          af[kh * 2 + kc], bf, acc[j], 0, 0, 0, 0x7F7F7F7F, 0, 0x7F7F7F7F);   \
    }                                                                         \
    _Pragma("unroll") for (int j = 0; j < 4; ++j)                             \
        _Pragma("unroll") for (int r = 0; r < 4; ++r)                         \
            vmax[r] = fmaxf(vmax[r], acc[j][r]);                              \
  }

  // prologue: phase 0 into buf0, fully landed before first compute
  STAGE(0, dst0);
  DRAINBAR;

  for (int np = 0; np < 8; ++np) {
    const int ns0 = np * 2;
    // phase ns0: compute buf0 while staging ns0+1 into buf1
    STAGE(ns0 + 1, dst1);
    COMPUTE_PHASE(lds_b[0]);
    DRAINBAR;  // buf1 writes landed; buf0 reads done before overwrite
    // phase ns0+1: compute buf1 while staging ns0+2 into buf0
    if (np < 7) STAGE(ns0 + 2, dst0);
    COMPUTE_PHASE(lds_b[1]);
    DRAINBAR;  // buf0 writes landed; buf1 reads done before overwrite
  }
#undef STAGE
#undef DRAINBAR
#undef COMPUTE_PHASE

  // cross-lane (16-lane col group) reduce + write per-image max: wsmx[img][row]
#pragma unroll
  for (int r = 0; r < 4; ++r) {
    float v = vmax[r];
#pragma unroll
    for (int off = 1; off < 16; off <<= 1) v = fmaxf(v, __shfl_xor(v, off));
    if (lcol == 0)
      wsmx[(size_t)img * 8192 + m0 + w * 16 + quad * 4 + r] = v;
  }
}

// ---------------------------------------------------------------------------
// epilogue_out: fused softmax + gating + transpose (R10-verified).
// Per block (p-tile, c-tile, b): (1) compute the FULL image-b softmax from
// wsmx[8][8192] (redundant across the image's 128 blocks; L2-hot);
// (2) out[b][co][p] = z[b*1024+p][co] * xw + b6[co] via LDS transpose.
__global__ __launch_bounds__(256) void epilogue_out(const short* __restrict__ z,
                                                    const float* __restrict__ wsmx,
                                                    const float* __restrict__ b6,
                                                    float* __restrict__ out) {
  const int p0 = blockIdx.x * 64, c0 = blockIdx.y * 64, b = blockIdx.z;
  __shared__ float t[64][65];  // t[co][p]
  __shared__ float ev[1024];   // exp(logit - bmax) for all pixels of image b
  __shared__ float red[2][4];  // per-wave partial max / sum
  const int u = threadIdx.x;

  // ---- fused softmax: thread u owns pixels u*4..u*4+3 of image b ----
  float lg[4];
  {
    float4 s4 = make_float4(0.f, 0.f, 0.f, 0.f);
#pragma unroll
    for (int img = 0; img < 8; ++img) {
      const float4 v = *(const float4*)&wsmx[(size_t)img * 8192 + b * 1024 + u * 4];
      s4.x += v.x; s4.y += v.y; s4.z += v.z; s4.w += v.w;
    }
    const float sc = 0.005524271728019903f;  // (1/8) * (1/sqrt(512))
    lg[0] = s4.x * sc; lg[1] = s4.y * sc; lg[2] = s4.z * sc; lg[3] = s4.w * sc;
  }
  float lmax = fmaxf(fmaxf(lg[0], lg[1]), fmaxf(lg[2], lg[3]));
#pragma unroll
  for (int off = 32; off >= 1; off >>= 1) lmax = fmaxf(lmax, __shfl_xor(lmax, off));
  if ((u & 63) == 0) red[0][u >> 6] = lmax;
  __syncthreads();
  const float bmax = fmaxf(fmaxf(red[0][0], red[0][1]), fmaxf(red[0][2], red[0][3]));
  float lsum = 0.f;
#pragma unroll
  for (int i = 0; i < 4; ++i) {
    const float e = expf(lg[i] - bmax);
    ev[u * 4 + i] = e;
    lsum += e;
  }
#pragma unroll
  for (int off = 32; off >= 1; off >>= 1) lsum += __shfl_xor(lsum, off);
  if ((u & 63) == 0) red[1][u >> 6] = lsum;

  // ---- stage z tile into LDS (transpose) while softmax sum settles ----
  {
    const int c4 = u & 15, pr = u >> 4;
    for (int pp = 0; pp < 4; ++pp) {
      const int p = pp * 16 + pr;
      const ushort4 v = *(const ushort4*)&z[((size_t)(b * 1024 + p0 + p)) * 512 + c0 + c4 * 4];
      t[c4 * 4 + 0][p] = bf2f(v.x);
      t[c4 * 4 + 1][p] = bf2f(v.y);
      t[c4 * 4 + 2][p] = bf2f(v.z);
      t[c4 * 4 + 3][p] = bf2f(v.w);
    }
  }
  __syncthreads();  // t[][] ready AND red[1]/ev[] ready
  const float inv_bsum = 1.f / (red[1][0] + red[1][1] + red[1][2] + red[1][3]);
  {
    const int p4 = u & 15, cr = u >> 4;
    const float4 wv = make_float4(ev[p0 + p4 * 4 + 0] * inv_bsum,
                                  ev[p0 + p4 * 4 + 1] * inv_bsum,
                                  ev[p0 + p4 * 4 + 2] * inv_bsum,
                                  ev[p0 + p4 * 4 + 3] * inv_bsum);
    for (int cc = 0; cc < 4; ++cc) {
      const int co = cc * 16 + cr;
      const float bias = b6[c0 + co];
      float4 o;
      o.x = t[co][p4 * 4 + 0] * wv.x + bias;
      o.y = t[co][p4 * 4 + 1] * wv.y + bias;
      o.z = t[co][p4 * 4 + 2] * wv.z + bias;
      o.w = t[co][p4 * 4 + 3] * wv.w + bias;
      *(float4*)&out[((size_t)(b * 512 + c0 + co)) * 1024 + p0 + p4 * 4] = o;
    }
  }
}

// ---------------------------------------------------------------------------
extern "C" void kernel_launch(void* const* d_in, const int* in_sizes, int n_in,
                              void* d_out, int out_size, void* d_ws, size_t ws_size,
                              hipStream_t stream) {
  const float* x  = (const float*)d_in[0];
  const float* Wq = (const float*)d_in[1];
  const float* bq = (const float*)d_in[2];
  const float* Wk = (const float*)d_in[3];
  const float* bk = (const float*)d_in[4];
  const float* W6 = (const float*)d_in[5];
  const float* b6 = (const float*)d_in[6];
  float* out = (float*)d_out;

  char* ws = (char*)d_ws;
  short* xt          = (short*)(ws + 0);               //  8 MB  bf16 [8192][512]
  short* wcat        = (short*)(ws + 8388608);         //  1.5MB bf16 [1536][512]
  unsigned char* qk8 = (unsigned char*)(ws + 10485760);//  8 MB  fp8  [8192][1024]
  short* z           = (short*)(ws + 18874368);        //  8 MB  bf16 [8192][512]
  float* wsmx        = (float*)(ws + 27262976);        // 256KB fp32 [8][8192]

  prep<<<1792, 256, 0, stream>>>(x, Wq, Wk, W6, xt, wcat);
  gemm_qkz<<<dim3(64, 12), 256, 0, stream>>>(xt, wcat, bq, bk, qk8, z);
  gemm_scores<<<dim3(64, 8), 512, 0, stream>>>(qk8, wsmx);
  epilogue_out<<<dim3(16, 8, 8), 256, 0, stream>>>(z, wsmx, b6, out);
}

// Round 17
// 151.194 us; speedup vs baseline: 1.0089x; 1.0089x over previous
//
#include <hip/hip_runtime.h>

// B=8, C=512, H=W=32, HW=1024, M=8192. scale = 1/sqrt(512).
// prep (x transpose->bf16, W pack->bf16)
// gemm_qkz (STAGED R5-hybrid: A per-lane global, B via global_load_lds,
//           8 barriers; q|k -> fp8 qk8 via v_cvt_pk_fp8_f32 (+bias), z -> bf16)
// gemm_scores (R17: TRUE counted-vmcnt pipeline (guide T3/T4 minimum form).
//              2 x 32 KB buffers; prologue stages phases 0+1 (8 loads/thread
//              in flight); per phase: s_waitcnt vmcnt(4) [own oldest 4 =
//              current buf; newer 4 STAY IN FLIGHT across both barriers] ->
//              raw s_barrier [no implicit drain] -> 16 MFMA -> raw barrier
//              -> stage ns+2 into freed buf. R16 lesson: drain-to-0 before
//              every barrier (explicit or implicit) is the ceiling mechanism;
//              counted vmcnt is the only way loads survive a barrier.
//              Per-wave vmcnt + all-waves-wait-before-barrier closes the
//              hazard graph explicitly. (kh,kc) order == R13 -> bit-identical.)
// epilogue_out (R10 fused softmax + gating + transpose, verified)

typedef __attribute__((ext_vector_type(8))) short bf16x8;
typedef __attribute__((ext_vector_type(4))) float f32x4;
typedef __attribute__((ext_vector_type(2))) long long i64x2;
typedef __attribute__((ext_vector_type(8))) int i32x8;

__device__ __forceinline__ unsigned short f2bf(float f) {
  unsigned u = __builtin_bit_cast(unsigned, f);
  u += 0x7FFFu + ((u >> 16) & 1u);
  return (unsigned short)(u >> 16);
}

__device__ __forceinline__ float bf2f(unsigned short b) {
  return __builtin_bit_cast(float, (unsigned)b << 16);
}

__device__ __forceinline__ void gload_lds16(const void* g, void* l) {
  __builtin_amdgcn_global_load_lds(
      (const __attribute__((address_space(1))) unsigned int*)g,
      (__attribute__((address_space(3))) unsigned int*)l, 16, 0, 0);
}

// ---------------------------------------------------------------------------
// prep: blocks [0,1024): transpose x [b][c][p] -> xt [b*1024+p][c] bf16
//       blocks [1024,1792): pack Wq|Wk|W6 -> wcat bf16 [1536][512]
__global__ __launch_bounds__(256) void prep(const float* __restrict__ x,
                                            const float* __restrict__ Wq,
                                            const float* __restrict__ Wk,
                                            const float* __restrict__ W6,
                                            short* __restrict__ xt,
                                            short* __restrict__ wcat) {
  const int bid = blockIdx.x, u = threadIdx.x;
  if (bid < 1024) {
    const int p0 = (bid & 15) * 64, c0 = ((bid >> 4) & 7) * 64, b = bid >> 7;
    __shared__ float t[64][65];
    {
      const int p4 = u & 15, cr = u >> 4;
      for (int cc = 0; cc < 4; ++cc) {
        const int c = cc * 16 + cr;
        const float4 v = *(const float4*)&x[((size_t)(b * 512 + c0 + c)) * 1024 + p0 + p4 * 4];
        t[p4 * 4 + 0][c] = v.x; t[p4 * 4 + 1][c] = v.y;
        t[p4 * 4 + 2][c] = v.z; t[p4 * 4 + 3][c] = v.w;
      }
    }
    __syncthreads();
    {
      const int c4 = u & 15, pr = u >> 4;
      for (int pp = 0; pp < 4; ++pp) {
        const int p = pp * 16 + pr;
        ushort4 o;
        o.x = f2bf(t[p][c4 * 4 + 0]); o.y = f2bf(t[p][c4 * 4 + 1]);
        o.z = f2bf(t[p][c4 * 4 + 2]); o.w = f2bf(t[p][c4 * 4 + 3]);
        *(ushort4*)&xt[((size_t)(b * 1024 + p0 + p)) * 512 + c0 + c4 * 4] = o;
      }
    }
  } else {
    const int i = (bid - 1024) * 256 + u;
    const int idx = i * 4;
    const float* src = (idx < 262144) ? Wq : (idx < 524288) ? Wk : W6;
    const float4 v = *(const float4*)&src[idx & 262143];
    ushort4 o;
    o.x = f2bf(v.x); o.y = f2bf(v.y); o.z = f2bf(v.z); o.w = f2bf(v.w);
    *(ushort4*)&wcat[idx] = o;
  }
}

// ---------------------------------------------------------------------------
// gemm_qkz: C[8192][1536] = xt @ wcat^T, R5-hybrid structure (staged).
// Block 128x128, grid (64,12); wave w owns rows [m0+w*32,+32): acc[2][8].
// A streamed per-lane from global; B staged in LDS in 4 K-chunks, 32 KB LDS.
// Cols 0..1023 -> qk8 fp8 (+bias, HW v_cvt_pk_fp8_f32); 1024..1535 -> z bf16.
__global__ __launch_bounds__(256) void gemm_qkz(const short* __restrict__ xt,
                                                const short* __restrict__ wcat,
                                                const float* __restrict__ bq,
                                                const float* __restrict__ bk,
                                                unsigned char* __restrict__ qk8,
                                                short* __restrict__ z) {
  __shared__ short lds_b[16384];  // 32 KB: 8 j-groups x 4 kb x 512 shorts
  const int tid = threadIdx.x, w = tid >> 6, lane = tid & 63;
  const int quad = lane >> 4, lcol = lane & 15;
  const int srow = lane & 15, skq = lane >> 4;  // staging: row in j-group, 8-elem quad
  const int m0 = blockIdx.x * 128, n0 = blockIdx.y * 128;

  f32x4 acc[2][8];
#pragma unroll
  for (int rg = 0; rg < 2; ++rg)
#pragma unroll
    for (int j = 0; j < 8; ++j)
#pragma unroll
      for (int r = 0; r < 4; ++r) acc[rg][j][r] = 0.f;

  // A: per-lane; row = m0 + w*32 + rg*16 + srow, k-elems kh*128 + kb*32 + skq*8
  const short* Abase = xt + (size_t)(m0 + w * 32 + srow) * 512 + skq * 8;
  // B: staging source; row = n0 + j*16 + srow
  const short* Bbase = wcat + (size_t)(n0 + srow) * 512 + skq * 8;

#pragma unroll
  for (int kh = 0; kh < 4; ++kh) {
    const int ke = kh * 128;  // k-elem base of this chunk
    __syncthreads();  // previous chunk fully consumed before overwrite
#pragma unroll
    for (int jj = 0; jj < 2; ++jj) {
      const int j = w * 2 + jj;
#pragma unroll
      for (int kb = 0; kb < 4; ++kb)
        gload_lds16(Bbase + (size_t)(j * 16) * 512 + ke + kb * 32,
                    lds_b + j * 2048 + kb * 512);
    }
    // prefetch this chunk's A (2 rg x 4 kb x 16 B) while glds are in flight
    bf16x8 af[2][4];
#pragma unroll
    for (int rg = 0; rg < 2; ++rg)
#pragma unroll
      for (int kb = 0; kb < 4; ++kb)
        af[rg][kb] = *(const bf16x8*)(Abase + (size_t)rg * 16 * 512 + ke + kb * 32);
    __syncthreads();  // B chunk ready
#pragma unroll
    for (int kb = 0; kb < 4; ++kb) {
#pragma unroll
      for (int j = 0; j < 8; ++j) {
        const bf16x8 bf = *(const bf16x8*)&lds_b[j * 2048 + kb * 512 + lane * 8];
#pragma unroll
        for (int rg = 0; rg < 2; ++rg)
          acc[rg][j] = __builtin_amdgcn_mfma_f32_16x16x32_bf16(af[rg][kb], bf, acc[rg][j], 0, 0, 0);
      }
    }
  }

  const int region = (int)blockIdx.y >> 2;  // 0=q, 1=k, 2=z (uniform per block)
  if (region < 2) {
    const float* bias = region ? bk : bq;
#pragma unroll
    for (int rg = 0; rg < 2; ++rg) {
      const int row = m0 + w * 32 + rg * 16 + quad * 4;
#pragma unroll
      for (int j = 0; j < 8; ++j) {
        const int col = n0 + j * 16 + lcol;
        const float bv = bias[col & 511];
        const int p01 = __builtin_amdgcn_cvt_pk_fp8_f32(
            acc[rg][j][0] + bv, acc[rg][j][1] + bv, 0, false);
        const int p23 = __builtin_amdgcn_cvt_pk_fp8_f32(
            acc[rg][j][2] + bv, acc[rg][j][3] + bv, 0, false);
        qk8[(size_t)(row + 0) * 1024 + col] = (unsigned char)(p01 & 0xFF);
        qk8[(size_t)(row + 1) * 1024 + col] = (unsigned char)((p01 >> 8) & 0xFF);
        qk8[(size_t)(row + 2) * 1024 + col] = (unsigned char)(p23 & 0xFF);
        qk8[(size_t)(row + 3) * 1024 + col] = (unsigned char)((p23 >> 8) & 0xFF);
      }
    }
  } else {
#pragma unroll
    for (int rg = 0; rg < 2; ++rg) {
      const int row = m0 + w * 32 + rg * 16 + quad * 4;
#pragma unroll
      for (int j = 0; j < 8; ++j) {
        const int col = n0 - 1024 + j * 16 + lcol;
#pragma unroll
        for (int r = 0; r < 4; ++r)
          z[(size_t)(row + r) * 512 + col] = (short)f2bf(acc[rg][j][r]);
      }
    }
  }
}

// ---------------------------------------------------------------------------
// gemm_scores R17: q @ k^T via MX-fp8 mfma_scale_f32_16x16x128_f8f6f4, unit
// scales. Counted-vmcnt pipeline (T3/T4 minimum form):
//   prologue: STAGE(0->buf0); STAGE(1->buf1)        [8 loads/thread in flight]
//   phase ns: s_waitcnt vmcnt(4)  [own oldest 4 = buf(ns&1) landed; per-wave
//             semantics: since EVERY wave waits its own before the barrier,
//             after the barrier ALL waves' buf(ns&1) writes have landed]
//             raw s_barrier  [no implicit drain -- prefetch stays in flight]
//             COMPUTE(buf(ns&1)) 16 MFMA
//             raw s_barrier  [all waves done reading before overwrite]
//             STAGE(ns+2 -> buf(ns&1))
//   last phase (ns=15): vmcnt(0) peel.
// Layout / staging split / lane maps / (kh,kc) accumulation order identical
// to R13/R16 -> bit-identical output. grid (64,8), block 512 = 8 waves;
// wave w owns rows [m0+w*16,+16); A resident af[4]; max -> wsmx[8][8192].
__global__ __launch_bounds__(512) void gemm_scores(const unsigned char* __restrict__ qk8,
                                                   float* __restrict__ wsmx) {
  __shared__ unsigned char lds_b[2][32768];  // per buf: 4 j x 2 kh x 2 kc x 2 p x 1 KB
  const int tid = threadIdx.x, w = tid >> 6, lane = tid & 63;
  const int quad = lane >> 4, lcol = lane & 15;
  const int srow = lane & 15, skb = (lane >> 4) * 32;  // staging row / k-offset
  const int m0 = blockIdx.x * 128;
  const int img = blockIdx.y;  // image = 1024-col stripe
  const int n0 = img * 1024;

  // A resident: row = m0 + w*16 + srow, k-bytes kk*128 + quad*32 + [0,32)
  const unsigned char* Abase = qk8 + (size_t)(m0 + w * 16 + srow) * 1024 + quad * 32;
  i32x8 af[4];
#pragma unroll
  for (int kk = 0; kk < 4; ++kk) af[kk] = *(const i32x8*)(Abase + kk * 128);

  // B staging: wave w stages j-group jg = w>>1, K-half kh2 = w&1.
  // Source row = n0 + ns*64 + jg*16 + srow; k-bytes: kh2*256 + kc*128 + skb + p*16.
  const int jg = w >> 1, kh2 = w & 1;
  const unsigned char* Bbase =
      qk8 + (size_t)(n0 + jg * 16 + srow) * 1024 + 512 + kh2 * 256 + skb;
  unsigned char* dst0 = &lds_b[0][jg * 8192 + kh2 * 4096];
  unsigned char* dst1 = &lds_b[1][jg * 8192 + kh2 * 4096];

  f32x4 acc[4];
  float vmax[4] = {-1e30f, -1e30f, -1e30f, -1e30f};

#define STAGE(ns, dst)                                                        \
  {                                                                           \
    _Pragma("unroll") for (int kc = 0; kc < 2; ++kc)                          \
        _Pragma("unroll") for (int p = 0; p < 2; ++p)                         \
            gload_lds16(Bbase + (ns) * 65536 + kc * 128 + p * 16,             \
                        (dst) + kc * 2048 + p * 1024);                        \
  }
#define COMPUTE_PHASE(CB)                                                     \
  {                                                                           \
    _Pragma("unroll") for (int j = 0; j < 4; ++j)                             \
        _Pragma("unroll") for (int r = 0; r < 4; ++r) acc[j][r] = 0.f;        \
    _Pragma("unroll") for (int kh = 0; kh < 2; ++kh)                          \
        _Pragma("unroll") for (int kc = 0; kc < 2; ++kc)                      \
            _Pragma("unroll") for (int j = 0; j < 4; ++j) {                   \
      i32x8 bf;                                                               \
      *(i64x2*)&bf =                                                          \
          *(const i64x2*)&(CB)[j * 8192 + kh * 4096 + kc * 2048 + lane * 16]; \
      *((i64x2*)&bf + 1) =                                                    \
          *(const i64x2*)&(CB)[j * 8192 + kh * 4096 + kc * 2048 + 1024 +      \
                               lane * 16];                                    \
      acc[j] = __builtin_amdgcn_mfma_scale_f32_16x16x128_f8f6f4(              \
          af[kh * 2 + kc], bf, acc[j], 0, 0, 0, 0x7F7F7F7F, 0, 0x7F7F7F7F);   \
    }                                                                         \
    _Pragma("unroll") for (int j = 0; j < 4; ++j)                             \
        _Pragma("unroll") for (int r = 0; r < 4; ++r)                         \
            vmax[r] = fmaxf(vmax[r], acc[j][r]);                              \
  }

  // prologue: two phases issued; 8 loads/thread in flight
  STAGE(0, dst0);
  STAGE(1, dst1);

  for (int ns = 0; ns < 16; ++ns) {
    if (ns < 15) {
      // wait own oldest 4 (current buf); newer 4 stay in flight across barriers
      asm volatile("s_waitcnt vmcnt(4)" ::: "memory");
    } else {
      asm volatile("s_waitcnt vmcnt(0)" ::: "memory");  // peel: drain last
    }
    __builtin_amdgcn_s_barrier();  // all waves' current-buf writes landed
    COMPUTE_PHASE(lds_b[ns & 1]);
    __builtin_amdgcn_s_barrier();  // all waves done reading before overwrite
    if (ns + 2 < 16) STAGE(ns + 2, (ns & 1) ? dst1 : dst0);
  }
#undef STAGE
#undef COMPUTE_PHASE

  // cross-lane (16-lane col group) reduce + write per-image max: wsmx[img][row]
#pragma unroll
  for (int r = 0; r < 4; ++r) {
    float v = vmax[r];
#pragma unroll
    for (int off = 1; off < 16; off <<= 1) v = fmaxf(v, __shfl_xor(v, off));
    if (lcol == 0)
      wsmx[(size_t)img * 8192 + m0 + w * 16 + quad * 4 + r] = v;
  }
}

// ---------------------------------------------------------------------------
// epilogue_out: fused softmax + gating + transpose (R10-verified).
// Per block (p-tile, c-tile, b): (1) compute the FULL image-b softmax from
// wsmx[8][8192] (redundant across the image's 128 blocks; L2-hot);
// (2) out[b][co][p] = z[b*1024+p][co] * xw + b6[co] via LDS transpose.
__global__ __launch_bounds__(256) void epilogue_out(const short* __restrict__ z,
                                                    const float* __restrict__ wsmx,
                                                    const float* __restrict__ b6,
                                                    float* __restrict__ out) {
  const int p0 = blockIdx.x * 64, c0 = blockIdx.y * 64, b = blockIdx.z;
  __shared__ float t[64][65];  // t[co][p]
  __shared__ float ev[1024];   // exp(logit - bmax) for all pixels of image b
  __shared__ float red[2][4];  // per-wave partial max / sum
  const int u = threadIdx.x;

  // ---- fused softmax: thread u owns pixels u*4..u*4+3 of image b ----
  float lg[4];
  {
    float4 s4 = make_float4(0.f, 0.f, 0.f, 0.f);
#pragma unroll
    for (int img = 0; img < 8; ++img) {
      const float4 v = *(const float4*)&wsmx[(size_t)img * 8192 + b * 1024 + u * 4];
      s4.x += v.x; s4.y += v.y; s4.z += v.z; s4.w += v.w;
    }
    const float sc = 0.005524271728019903f;  // (1/8) * (1/sqrt(512))
    lg[0] = s4.x * sc; lg[1] = s4.y * sc; lg[2] = s4.z * sc; lg[3] = s4.w * sc;
  }
  float lmax = fmaxf(fmaxf(lg[0], lg[1]), fmaxf(lg[2], lg[3]));
#pragma unroll
  for (int off = 32; off >= 1; off >>= 1) lmax = fmaxf(lmax, __shfl_xor(lmax, off));
  if ((u & 63) == 0) red[0][u >> 6] = lmax;
  __syncthreads();
  const float bmax = fmaxf(fmaxf(red[0][0], red[0][1]), fmaxf(red[0][2], red[0][3]));
  float lsum = 0.f;
#pragma unroll
  for (int i = 0; i < 4; ++i) {
    const float e = expf(lg[i] - bmax);
    ev[u * 4 + i] = e;
    lsum += e;
  }
#pragma unroll
  for (int off = 32; off >= 1; off >>= 1) lsum += __shfl_xor(lsum, off);
  if ((u & 63) == 0) red[1][u >> 6] = lsum;

  // ---- stage z tile into LDS (transpose) while softmax sum settles ----
  {
    const int c4 = u & 15, pr = u >> 4;
    for (int pp = 0; pp < 4; ++pp) {
      const int p = pp * 16 + pr;
      const ushort4 v = *(const ushort4*)&z[((size_t)(b * 1024 + p0 + p)) * 512 + c0 + c4 * 4];
      t[c4 * 4 + 0][p] = bf2f(v.x);
      t[c4 * 4 + 1][p] = bf2f(v.y);
      t[c4 * 4 + 2][p] = bf2f(v.z);
      t[c4 * 4 + 3][p] = bf2f(v.w);
    }
  }
  __syncthreads();  // t[][] ready AND red[1]/ev[] ready
  const float inv_bsum = 1.f / (red[1][0] + red[1][1] + red[1][2] + red[1][3]);
  {
    const int p4 = u & 15, cr = u >> 4;
    const float4 wv = make_float4(ev[p0 + p4 * 4 + 0] * inv_bsum,
                                  ev[p0 + p4 * 4 + 1] * inv_bsum,
                                  ev[p0 + p4 * 4 + 2] * inv_bsum,
                                  ev[p0 + p4 * 4 + 3] * inv_bsum);
    for (int cc = 0; cc < 4; ++cc) {
      const int co = cc * 16 + cr;
      const float bias = b6[c0 + co];
      float4 o;
      o.x = t[co][p4 * 4 + 0] * wv.x + bias;
      o.y = t[co][p4 * 4 + 1] * wv.y + bias;
      o.z = t[co][p4 * 4 + 2] * wv.z + bias;
      o.w = t[co][p4 * 4 + 3] * wv.w + bias;
      *(float4*)&out[((size_t)(b * 512 + c0 + co)) * 1024 + p0 + p4 * 4] = o;
    }
  }
}

// ---------------------------------------------------------------------------
extern "C" void kernel_launch(void* const* d_in, const int* in_sizes, int n_in,
                              void* d_out, int out_size, void* d_ws, size_t ws_size,
                              hipStream_t stream) {
  const float* x  = (const float*)d_in[0];
  const float* Wq = (const float*)d_in[1];
  const float* bq = (const float*)d_in[2];
  const float* Wk = (const float*)d_in[3];
  const float* bk = (const float*)d_in[4];
  const float* W6 = (const float*)d_in[5];
  const float* b6 = (const float*)d_in[6];
  float* out = (float*)d_out;

  char* ws = (char*)d_ws;
  short* xt          = (short*)(ws + 0);               //  8 MB  bf16 [8192][512]
  short* wcat        = (short*)(ws + 8388608);         //  1.5MB bf16 [1536][512]
  unsigned char* qk8 = (unsigned char*)(ws + 10485760);//  8 MB  fp8  [8192][1024]
  short* z           = (short*)(ws + 18874368);        //  8 MB  bf16 [8192][512]
  float* wsmx        = (float*)(ws + 27262976);        // 256KB fp32 [8][8192]

  prep<<<1792, 256, 0, stream>>>(x, Wq, Wk, W6, xt, wcat);
  gemm_qkz<<<dim3(64, 12), 256, 0, stream>>>(xt, wcat, bq, bk, qk8, z);
  gemm_scores<<<dim3(64, 8), 512, 0, stream>>>(qk8, wsmx);
  epilogue_out<<<dim3(16, 8, 8), 256, 0, stream>>>(z, wsmx, b6, out);
}

// Round 18
// 149.406 us; speedup vs baseline: 1.0210x; 1.0120x over previous
//
#include <hip/hip_runtime.h>

// B=8, C=512, H=W=32, HW=1024, M=8192. scale = 1/sqrt(512).
// prep (x transpose->bf16, W pack->bf16)
// gemm_qkz (R18: counted-vmcnt half-chunk pipeline, same pattern as R17
//           scores (HW-validated). 8 half-chunks x 16 KB, double-buffered in
//           the SAME 32 KB LDS (no occupancy change). Per half: vmcnt(4) ->
//           raw barrier -> 32 MFMA -> raw barrier -> stage h+2. vmcnt(4) is
//           robust to A-load scheduling: gload_lds intrinsics can't reorder
//           among themselves, so newest-4 == B(h+1) always -> B(h) landed.
//           (kh,kb) accumulation order unchanged -> bit-identical.)
// gemm_scores (R17: counted-vmcnt pipeline, 2 x 32 KB, vmcnt(4)/raw
//              barriers, verified bit-identical, session best)
// epilogue_out (R10 fused softmax + gating + transpose, verified)

typedef __attribute__((ext_vector_type(8))) short bf16x8;
typedef __attribute__((ext_vector_type(4))) float f32x4;
typedef __attribute__((ext_vector_type(2))) long long i64x2;
typedef __attribute__((ext_vector_type(8))) int i32x8;

__device__ __forceinline__ unsigned short f2bf(float f) {
  unsigned u = __builtin_bit_cast(unsigned, f);
  u += 0x7FFFu + ((u >> 16) & 1u);
  return (unsigned short)(u >> 16);
}

__device__ __forceinline__ float bf2f(unsigned short b) {
  return __builtin_bit_cast(float, (unsigned)b << 16);
}

__device__ __forceinline__ void gload_lds16(const void* g, void* l) {
  __builtin_amdgcn_global_load_lds(
      (const __attribute__((address_space(1))) unsigned int*)g,
      (__attribute__((address_space(3))) unsigned int*)l, 16, 0, 0);
}

// ---------------------------------------------------------------------------
// prep: blocks [0,1024): transpose x [b][c][p] -> xt [b*1024+p][c] bf16
//       blocks [1024,1792): pack Wq|Wk|W6 -> wcat bf16 [1536][512]
__global__ __launch_bounds__(256) void prep(const float* __restrict__ x,
                                            const float* __restrict__ Wq,
                                            const float* __restrict__ Wk,
                                            const float* __restrict__ W6,
                                            short* __restrict__ xt,
                                            short* __restrict__ wcat) {
  const int bid = blockIdx.x, u = threadIdx.x;
  if (bid < 1024) {
    const int p0 = (bid & 15) * 64, c0 = ((bid >> 4) & 7) * 64, b = bid >> 7;
    __shared__ float t[64][65];
    {
      const int p4 = u & 15, cr = u >> 4;
      for (int cc = 0; cc < 4; ++cc) {
        const int c = cc * 16 + cr;
        const float4 v = *(const float4*)&x[((size_t)(b * 512 + c0 + c)) * 1024 + p0 + p4 * 4];
        t[p4 * 4 + 0][c] = v.x; t[p4 * 4 + 1][c] = v.y;
        t[p4 * 4 + 2][c] = v.z; t[p4 * 4 + 3][c] = v.w;
      }
    }
    __syncthreads();
    {
      const int c4 = u & 15, pr = u >> 4;
      for (int pp = 0; pp < 4; ++pp) {
        const int p = pp * 16 + pr;
        ushort4 o;
        o.x = f2bf(t[p][c4 * 4 + 0]); o.y = f2bf(t[p][c4 * 4 + 1]);
        o.z = f2bf(t[p][c4 * 4 + 2]); o.w = f2bf(t[p][c4 * 4 + 3]);
        *(ushort4*)&xt[((size_t)(b * 1024 + p0 + p)) * 512 + c0 + c4 * 4] = o;
      }
    }
  } else {
    const int i = (bid - 1024) * 256 + u;
    const int idx = i * 4;
    const float* src = (idx < 262144) ? Wq : (idx < 524288) ? Wk : W6;
    const float4 v = *(const float4*)&src[idx & 262143];
    ushort4 o;
    o.x = f2bf(v.x); o.y = f2bf(v.y); o.z = f2bf(v.z); o.w = f2bf(v.w);
    *(ushort4*)&wcat[idx] = o;
  }
}

// ---------------------------------------------------------------------------
// gemm_qkz R18: C[8192][1536] = xt @ wcat^T, counted-vmcnt half-chunk
// pipeline. Block 128x128, grid (64,12); wave w owns rows [m0+w*32,+32):
// acc[2][8]. 8 half-chunks h (kh = h>>1, kb-pair = h&1), each 16 KB of B
// staged (4 gload_lds/thread), double-buffered in 32 KB LDS.
//   prologue: B(0)->buf0, A(0); B(1)->buf1, A(1)
//   half h:  vmcnt(4) [h<7; newest-4 == B(h+1) -> B(h) landed] / vmcnt(0) [h=7]
//            raw s_barrier ; compute 32 MFMA (2 kb2 x 8 j x 2 rg) ;
//            raw s_barrier ; stage B(h+2)->buf(h&1), load A(h+2)->af(h&1)
// Per-element (kh,kb) accumulation order == staged version -> bit-identical.
// Cols 0..1023 -> qk8 fp8 (+bias, HW v_cvt_pk_fp8_f32); 1024..1535 -> z bf16.
__global__ __launch_bounds__(256) void gemm_qkz(const short* __restrict__ xt,
                                                const short* __restrict__ wcat,
                                                const float* __restrict__ bq,
                                                const float* __restrict__ bk,
                                                unsigned char* __restrict__ qk8,
                                                short* __restrict__ z) {
  __shared__ short lds_b[2][8192];  // per buf: 8 j x 2 kb2 x 512 shorts = 16 KB
  const int tid = threadIdx.x, w = tid >> 6, lane = tid & 63;
  const int quad = lane >> 4, lcol = lane & 15;
  const int srow = lane & 15, skq = lane >> 4;  // staging: row in j-group, 8-elem quad
  const int m0 = blockIdx.x * 128, n0 = blockIdx.y * 128;

  f32x4 acc[2][8];
#pragma unroll
  for (int rg = 0; rg < 2; ++rg)
#pragma unroll
    for (int j = 0; j < 8; ++j)
#pragma unroll
      for (int r = 0; r < 4; ++r) acc[rg][j][r] = 0.f;

  // A: per-lane; row = m0 + w*32 + rg*16 + srow, k-elems h*64 + kb2*32 + skq*8
  const short* Abase = xt + (size_t)(m0 + w * 32 + srow) * 512 + skq * 8;
  // B: staging source; row = n0 + j*16 + srow, k-elems h*64 + kb2*32 + skq*8
  const short* Bbase = wcat + (size_t)(n0 + srow) * 512 + skq * 8;

  bf16x8 af[2][2][2];  // [h&1][rg][kb2]

#define STAGE_B(h, buf)                                                       \
  {                                                                           \
    _Pragma("unroll") for (int jj = 0; jj < 2; ++jj) {                        \
      const int j = w * 2 + jj;                                               \
      _Pragma("unroll") for (int kb2 = 0; kb2 < 2; ++kb2)                     \
          gload_lds16(Bbase + (size_t)(j * 16) * 512 + (h) * 64 + kb2 * 32,   \
                      &lds_b[buf][j * 1024 + kb2 * 512]);                     \
    }                                                                         \
  }
#define LOAD_A(h, sl)                                                         \
  {                                                                           \
    _Pragma("unroll") for (int rg = 0; rg < 2; ++rg)                          \
        _Pragma("unroll") for (int kb2 = 0; kb2 < 2; ++kb2)                   \
            af[sl][rg][kb2] = *(const bf16x8*)(Abase +                        \
                (size_t)rg * 16 * 512 + (h) * 64 + kb2 * 32);                 \
  }

  // prologue: two half-chunks in flight
  STAGE_B(0, 0);
  LOAD_A(0, 0);
  STAGE_B(1, 1);
  LOAD_A(1, 1);

#pragma unroll
  for (int h = 0; h < 8; ++h) {
    if (h < 7) {
      // newest 4 vmem ops are B(h+1)'s stages -> B(h) landed; prefetch survives
      asm volatile("s_waitcnt vmcnt(4)" ::: "memory");
    } else {
      asm volatile("s_waitcnt vmcnt(0)" ::: "memory");  // peel: drain last
    }
    __builtin_amdgcn_s_barrier();  // all waves' buf(h&1) writes landed
#pragma unroll
    for (int kb2 = 0; kb2 < 2; ++kb2) {
#pragma unroll
      for (int j = 0; j < 8; ++j) {
        const bf16x8 bf = *(const bf16x8*)&lds_b[h & 1][j * 1024 + kb2 * 512 + lane * 8];
#pragma unroll
        for (int rg = 0; rg < 2; ++rg)
          acc[rg][j] = __builtin_amdgcn_mfma_f32_16x16x32_bf16(
              af[h & 1][rg][kb2], bf, acc[rg][j], 0, 0, 0);
      }
    }
    __builtin_amdgcn_s_barrier();  // all waves done reading before overwrite
    if (h + 2 < 8) {
      STAGE_B(h + 2, h & 1);
      LOAD_A(h + 2, h & 1);
    }
  }
#undef STAGE_B
#undef LOAD_A

  const int region = (int)blockIdx.y >> 2;  // 0=q, 1=k, 2=z (uniform per block)
  if (region < 2) {
    const float* bias = region ? bk : bq;
#pragma unroll
    for (int rg = 0; rg < 2; ++rg) {
      const int row = m0 + w * 32 + rg * 16 + quad * 4;
#pragma unroll
      for (int j = 0; j < 8; ++j) {
        const int col = n0 + j * 16 + lcol;
        const float bv = bias[col & 511];
        const int p01 = __builtin_amdgcn_cvt_pk_fp8_f32(
            acc[rg][j][0] + bv, acc[rg][j][1] + bv, 0, false);
        const int p23 = __builtin_amdgcn_cvt_pk_fp8_f32(
            acc[rg][j][2] + bv, acc[rg][j][3] + bv, 0, false);
        qk8[(size_t)(row + 0) * 1024 + col] = (unsigned char)(p01 & 0xFF);
        qk8[(size_t)(row + 1) * 1024 + col] = (unsigned char)((p01 >> 8) & 0xFF);
        qk8[(size_t)(row + 2) * 1024 + col] = (unsigned char)(p23 & 0xFF);
        qk8[(size_t)(row + 3) * 1024 + col] = (unsigned char)((p23 >> 8) & 0xFF);
      }
    }
  } else {
#pragma unroll
    for (int rg = 0; rg < 2; ++rg) {
      const int row = m0 + w * 32 + rg * 16 + quad * 4;
#pragma unroll
      for (int j = 0; j < 8; ++j) {
        const int col = n0 - 1024 + j * 16 + lcol;
#pragma unroll
        for (int r = 0; r < 4; ++r)
          z[(size_t)(row + r) * 512 + col] = (short)f2bf(acc[rg][j][r]);
      }
    }
  }
}

// ---------------------------------------------------------------------------
// gemm_scores R17 (verified, session best): q @ k^T via MX-fp8
// mfma_scale_f32_16x16x128_f8f6f4, unit scales. Counted-vmcnt pipeline:
//   prologue: STAGE(0->buf0); STAGE(1->buf1)
//   phase ns: vmcnt(4) [own oldest 4 = current buf landed; newer 4 stay in
//             flight across both raw barriers] -> s_barrier -> 16 MFMA ->
//             s_barrier -> STAGE(ns+2). Last phase peels vmcnt(0).
// grid (64,8), block 512 = 8 waves; wave w owns rows [m0+w*16,+16);
// A resident af[4]; per-image row-max -> wsmx[8][8192]. Bit-identical.
__global__ __launch_bounds__(512) void gemm_scores(const unsigned char* __restrict__ qk8,
                                                   float* __restrict__ wsmx) {
  __shared__ unsigned char lds_b[2][32768];  // per buf: 4 j x 2 kh x 2 kc x 2 p x 1 KB
  const int tid = threadIdx.x, w = tid >> 6, lane = tid & 63;
  const int quad = lane >> 4, lcol = lane & 15;
  const int srow = lane & 15, skb = (lane >> 4) * 32;  // staging row / k-offset
  const int m0 = blockIdx.x * 128;
  const int img = blockIdx.y;  // image = 1024-col stripe
  const int n0 = img * 1024;

  // A resident: row = m0 + w*16 + srow, k-bytes kk*128 + quad*32 + [0,32)
  const unsigned char* Abase = qk8 + (size_t)(m0 + w * 16 + srow) * 1024 + quad * 32;
  i32x8 af[4];
#pragma unroll
  for (int kk = 0; kk < 4; ++kk) af[kk] = *(const i32x8*)(Abase + kk * 128);

  // B staging: wave w stages j-group jg = w>>1, K-half kh2 = w&1.
  // Source row = n0 + ns*64 + jg*16 + srow; k-bytes: kh2*256 + kc*128 + skb + p*16.
  const int jg = w >> 1, kh2 = w & 1;
  const unsigned char* Bbase =
      qk8 + (size_t)(n0 + jg * 16 + srow) * 1024 + 512 + kh2 * 256 + skb;
  unsigned char* dst0 = &lds_b[0][jg * 8192 + kh2 * 4096];
  unsigned char* dst1 = &lds_b[1][jg * 8192 + kh2 * 4096];

  f32x4 acc[4];
  float vmax[4] = {-1e30f, -1e30f, -1e30f, -1e30f};

#define STAGE(ns, dst)                                                        \
  {                                                                           \
    _Pragma("unroll") for (int kc = 0; kc < 2; ++kc)                          \
        _Pragma("unroll") for (int p = 0; p < 2; ++p)                         \
            gload_lds16(Bbase + (ns) * 65536 + kc * 128 + p * 16,             \
                        (dst) + kc * 2048 + p * 1024);                        \
  }
#define COMPUTE_PHASE(CB)                                                     \
  {                                                                           \
    _Pragma("unroll") for (int j = 0; j < 4; ++j)                             \
        _Pragma("unroll") for (int r = 0; r < 4; ++r) acc[j][r] = 0.f;        \
    _Pragma("unroll") for (int kh = 0; kh < 2; ++kh)                          \
        _Pragma("unroll") for (int kc = 0; kc < 2; ++kc)                      \
            _Pragma("unroll") for (int j = 0; j < 4; ++j) {                   \
      i32x8 bf;                                                               \
      *(i64x2*)&bf =                                                          \
          *(const i64x2*)&(CB)[j * 8192 + kh * 4096 + kc * 2048 + lane * 16]; \
      *((i64x2*)&bf + 1) =                                                    \
          *(const i64x2*)&(CB)[j * 8192 + kh * 4096 + kc * 2048 + 1024 +      \
                               lane * 16];                                    \
      acc[j] = __builtin_amdgcn_mfma_scale_f32_16x16x128_f8f6f4(              \
          af[kh * 2 + kc], bf, acc[j], 0, 0, 0, 0x7F7F7F7F, 0, 0x7F7F7F7F);   \
    }                                                                         \
    _Pragma("unroll") for (int j = 0; j < 4; ++j)                             \
        _Pragma("unroll") for (int r = 0; r < 4; ++r)                         \
            vmax[r] = fmaxf(vmax[r], acc[j][r]);                              \
  }

  // prologue: two phases issued; 8 loads/thread in flight
  STAGE(0, dst0);
  STAGE(1, dst1);

  for (int ns = 0; ns < 16; ++ns) {
    if (ns < 15) {
      asm volatile("s_waitcnt vmcnt(4)" ::: "memory");
    } else {
      asm volatile("s_waitcnt vmcnt(0)" ::: "memory");  // peel: drain last
    }
    __builtin_amdgcn_s_barrier();  // all waves' current-buf writes landed
    COMPUTE_PHASE(lds_b[ns & 1]);
    __builtin_amdgcn_s_barrier();  // all waves done reading before overwrite
    if (ns + 2 < 16) STAGE(ns + 2, (ns & 1) ? dst1 : dst0);
  }
#undef STAGE
#undef COMPUTE_PHASE

  // cross-lane (16-lane col group) reduce + write per-image max: wsmx[img][row]
#pragma unroll
  for (int r = 0; r < 4; ++r) {
    float v = vmax[r];
#pragma unroll
    for (int off = 1; off < 16; off <<= 1) v = fmaxf(v, __shfl_xor(v, off));
    if (lcol == 0)
      wsmx[(size_t)img * 8192 + m0 + w * 16 + quad * 4 + r] = v;
  }
}

// ---------------------------------------------------------------------------
// epilogue_out: fused softmax + gating + transpose (R10-verified).
// Per block (p-tile, c-tile, b): (1) compute the FULL image-b softmax from
// wsmx[8][8192] (redundant across the image's 128 blocks; L2-hot);
// (2) out[b][co][p] = z[b*1024+p][co] * xw + b6[co] via LDS transpose.
__global__ __launch_bounds__(256) void epilogue_out(const short* __restrict__ z,
                                                    const float* __restrict__ wsmx,
                                                    const float* __restrict__ b6,
                                                    float* __restrict__ out) {
  const int p0 = blockIdx.x * 64, c0 = blockIdx.y * 64, b = blockIdx.z;
  __shared__ float t[64][65];  // t[co][p]
  __shared__ float ev[1024];   // exp(logit - bmax) for all pixels of image b
  __shared__ float red[2][4];  // per-wave partial max / sum
  const int u = threadIdx.x;

  // ---- fused softmax: thread u owns pixels u*4..u*4+3 of image b ----
  float lg[4];
  {
    float4 s4 = make_float4(0.f, 0.f, 0.f, 0.f);
#pragma unroll
    for (int img = 0; img < 8; ++img) {
      const float4 v = *(const float4*)&wsmx[(size_t)img * 8192 + b * 1024 + u * 4];
      s4.x += v.x; s4.y += v.y; s4.z += v.z; s4.w += v.w;
    }
    const float sc = 0.005524271728019903f;  // (1/8) * (1/sqrt(512))
    lg[0] = s4.x * sc; lg[1] = s4.y * sc; lg[2] = s4.z * sc; lg[3] = s4.w * sc;
  }
  float lmax = fmaxf(fmaxf(lg[0], lg[1]), fmaxf(lg[2], lg[3]));
#pragma unroll
  for (int off = 32; off >= 1; off >>= 1) lmax = fmaxf(lmax, __shfl_xor(lmax, off));
  if ((u & 63) == 0) red[0][u >> 6] = lmax;
  __syncthreads();
  const float bmax = fmaxf(fmaxf(red[0][0], red[0][1]), fmaxf(red[0][2], red[0][3]));
  float lsum = 0.f;
#pragma unroll
  for (int i = 0; i < 4; ++i) {
    const float e = expf(lg[i] - bmax);
    ev[u * 4 + i] = e;
    lsum += e;
  }
#pragma unroll
  for (int off = 32; off >= 1; off >>= 1) lsum += __shfl_xor(lsum, off);
  if ((u & 63) == 0) red[1][u >> 6] = lsum;

  // ---- stage z tile into LDS (transpose) while softmax sum settles ----
  {
    const int c4 = u & 15, pr = u >> 4;
    for (int pp = 0; pp < 4; ++pp) {
      const int p = pp * 16 + pr;
      const ushort4 v = *(const ushort4*)&z[((size_t)(b * 1024 + p0 + p)) * 512 + c0 + c4 * 4];
      t[c4 * 4 + 0][p] = bf2f(v.x);
      t[c4 * 4 + 1][p] = bf2f(v.y);
      t[c4 * 4 + 2][p] = bf2f(v.z);
      t[c4 * 4 + 3][p] = bf2f(v.w);
    }
  }
  __syncthreads();  // t[][] ready AND red[1]/ev[] ready
  const float inv_bsum = 1.f / (red[1][0] + red[1][1] + red[1][2] + red[1][3]);
  {
    const int p4 = u & 15, cr = u >> 4;
    const float4 wv = make_float4(ev[p0 + p4 * 4 + 0] * inv_bsum,
                                  ev[p0 + p4 * 4 + 1] * inv_bsum,
                                  ev[p0 + p4 * 4 + 2] * inv_bsum,
                                  ev[p0 + p4 * 4 + 3] * inv_bsum);
    for (int cc = 0; cc < 4; ++cc) {
      const int co = cc * 16 + cr;
      const float bias = b6[c0 + co];
      float4 o;
      o.x = t[co][p4 * 4 + 0] * wv.x + bias;
      o.y = t[co][p4 * 4 + 1] * wv.y + bias;
      o.z = t[co][p4 * 4 + 2] * wv.z + bias;
      o.w = t[co][p4 * 4 + 3] * wv.w + bias;
      *(float4*)&out[((size_t)(b * 512 + c0 + co)) * 1024 + p0 + p4 * 4] = o;
    }
  }
}

// ---------------------------------------------------------------------------
extern "C" void kernel_launch(void* const* d_in, const int* in_sizes, int n_in,
                              void* d_out, int out_size, void* d_ws, size_t ws_size,
                              hipStream_t stream) {
  const float* x  = (const float*)d_in[0];
  const float* Wq = (const float*)d_in[1];
  const float* bq = (const float*)d_in[2];
  const float* Wk = (const float*)d_in[3];
  const float* bk = (const float*)d_in[4];
  const float* W6 = (const float*)d_in[5];
  const float* b6 = (const float*)d_in[6];
  float* out = (float*)d_out;

  char* ws = (char*)d_ws;
  short* xt          = (short*)(ws + 0);               //  8 MB  bf16 [8192][512]
  short* wcat        = (short*)(ws + 8388608);         //  1.5MB bf16 [1536][512]
  unsigned char* qk8 = (unsigned char*)(ws + 10485760);//  8 MB  fp8  [8192][1024]
  short* z           = (short*)(ws + 18874368);        //  8 MB  bf16 [8192][512]
  float* wsmx        = (float*)(ws + 27262976);        // 256KB fp32 [8][8192]

  prep<<<1792, 256, 0, stream>>>(x, Wq, Wk, W6, xt, wcat);
  gemm_qkz<<<dim3(64, 12), 256, 0, stream>>>(xt, wcat, bq, bk, qk8, z);
  gemm_scores<<<dim3(64, 8), 512, 0, stream>>>(qk8, wsmx);
  epilogue_out<<<dim3(16, 8, 8), 256, 0, stream>>>(z, wsmx, b6, out);
}